// Round 16
// baseline (1856.856 us; speedup 1.0000x reference)
//
#include <hip/hip_runtime.h>

#define NN   51200
#define EE   819200
#define GG   256
#define NN2  102400
#define AA   204800
#define EE2  409600
#define DD   64
#define LL   5

typedef __attribute__((ext_vector_type(8))) short bf16x8;
typedef __attribute__((ext_vector_type(4))) float f32x4;
typedef unsigned short ushort_t;

// ---------------- workspace layout (bytes) ----------------
#define OFF_H      ((size_t)0)          // emb h; post-GIN: yrel spans OFF_H..OFF_H2
#define OFF_AGG    ((size_t)13107200)   // GIN: h ping-pong buffer B
#define OFF_H2     ((size_t)26214400)   // GIN: buffer A; layer-4 output = h2 (alive to kpoolg)
#define OFF_XP     ((size_t)39321600)   // front 4.9 MB: rank1/rank2 during CSR build
#define OFF_YROOT  ((size_t)65536000)   // prepped bf16 weights during GIN; yroot after
#define OFF_OFFS1  ((size_t)91750400)
#define OFF_COL1   ((size_t)91955216)
#define OFF_OFFS2  ((size_t)95232016)
#define OFF_COL2   ((size_t)95641632)
#define OFF_CNT1   ((size_t)97280032)   // zeroed region starts here
#define OFF_CUR1   ((size_t)97484832)   // pstat2[5][32][128] during GIN (zeroed by memset)
#define OFF_CNT2   ((size_t)97689632)
#define OFF_CUR2   ((size_t)98099232)
#define OFF_STATS  ((size_t)98508832)
#define ZERO_BYTES ((size_t)1231360)
#define OFF_ISO    ((size_t)98511392)
#define OFF_M      ((size_t)98920992)
#define WS_NEEDED  ((size_t)99052064)

__device__ __forceinline__ int waveInclScan(int v, int lane) {
#pragma unroll
    for (int off = 1; off < 64; off <<= 1) {
        int t = __shfl_up(v, off, 64);
        if (lane >= off) v += t;
    }
    return v;
}

// ---------------- split-bf16 helpers ----------------
__device__ __forceinline__ void bsplit(float x, ushort_t& hi, ushort_t& lo) {
    union { float f; unsigned u; } a; a.f = x;
    unsigned hb = (a.u + 0x7FFFu + ((a.u >> 16) & 1u)) >> 16;   // RNE to bf16
    union { unsigned u; float f; } h; h.u = hb << 16;
    float r = x - h.f;
    union { float f; unsigned u; } b; b.f = r;
    unsigned lb = (b.u + 0x7FFFu + ((b.u >> 16) & 1u)) >> 16;
    hi = (ushort_t)hb; lo = (ushort_t)lb;
}

// ---------------- CSR histogram + rank capture (R11 structure — measured best) ----------------
__global__ void khist_m(const int* __restrict__ dst1, const int* __restrict__ dst2,
                        int* __restrict__ cnt1, int* __restrict__ cnt2,
                        int* __restrict__ rank1, int* __restrict__ rank2) {
    int b = blockIdx.x;
    if (b < 800) {
        int i = (b * 256 + threadIdx.x) * 4;
        int4 d = *(const int4*)(dst1 + i);
        int4 r;
        r.x = atomicAdd(&cnt1[d.x], 1);
        r.y = atomicAdd(&cnt1[d.y], 1);
        r.z = atomicAdd(&cnt1[d.z], 1);
        r.w = atomicAdd(&cnt1[d.w], 1);
        *(int4*)(rank1 + i) = r;
    } else {
        int i = ((b - 800) * 256 + threadIdx.x) * 4;
        int4 d = *(const int4*)(dst2 + i);
        int4 r;
        r.x = atomicAdd(&cnt2[d.x], 1);
        r.y = atomicAdd(&cnt2[d.y], 1);
        r.z = atomicAdd(&cnt2[d.z], 1);
        r.w = atomicAdd(&cnt2[d.w], 1);
        *(int4*)(rank2 + i) = r;
    }
}

__global__ void kreduce_m(const int* __restrict__ cnt1, const int* __restrict__ cnt2,
                          int* __restrict__ bsum1, int* __restrict__ bsum2) {
    __shared__ int wsr[4];
    int b = blockIdx.x;
    const int* cnt; int* bsum;
    if (b < 50) { cnt = cnt1; bsum = bsum1; }
    else { b -= 50; cnt = cnt2; bsum = bsum2; }
    int tid = threadIdx.x, lane = tid & 63, wid = tid >> 6;
    int4 v = ((const int4*)(cnt + (size_t)b * 1024))[tid];
    int s = v.x + v.y + v.z + v.w;
#pragma unroll
    for (int off = 32; off; off >>= 1) s += __shfl_down(s, off, 64);
    if (lane == 0) wsr[wid] = s;
    __syncthreads();
    if (tid == 0) bsum[b] = wsr[0] + wsr[1] + wsr[2] + wsr[3];
}

__global__ void kscan_small_m(const int* __restrict__ bsum1, const int* __restrict__ bsum2,
                              int* __restrict__ boffs1, int* __restrict__ boffs2) {
    __shared__ int w0s;
    const int* bsum = blockIdx.x ? bsum2 : bsum1;
    int* boffs = blockIdx.x ? boffs2 : boffs1;
    int nb = blockIdx.x ? 100 : 50;
    int tid = threadIdx.x, lane = tid & 63, wid = tid >> 6;
    int v = (tid < nb) ? bsum[tid] : 0;
    int incl = waveInclScan(v, lane);
    if (tid == 63) w0s = incl;
    __syncthreads();
    int excl = incl - v + (wid ? w0s : 0);
    if (tid < nb) boffs[tid] = excl;
}

__global__ void kscan_apply_m(const int* __restrict__ cnt1, const int* __restrict__ cnt2,
                              const int* __restrict__ boffs1, const int* __restrict__ boffs2,
                              int* __restrict__ offs1, int* __restrict__ offs2) {
    __shared__ int wsum[4];
    int b = blockIdx.x;
    const int* cnt; const int* boffs; int* offs; int n, total;
    if (b < 50) { cnt = cnt1; boffs = boffs1; offs = offs1; n = NN; total = EE; }
    else { b -= 50; cnt = cnt2; boffs = boffs2; offs = offs2; n = NN2; total = EE2; }
    int tid = threadIdx.x, lane = tid & 63, wid = tid >> 6;
    size_t base = (size_t)b * 1024;
    int4 v = ((const int4*)(cnt + base))[tid];
    int s = v.x + v.y + v.z + v.w;
    int incl = waveInclScan(s, lane);
    if (lane == 63) wsum[wid] = incl;
    __syncthreads();
    int woff = boffs[b];
#pragma unroll
    for (int w = 0; w < 3; ++w) woff += (w < wid) ? wsum[w] : 0;
    int excl = woff + incl - s;
    int4 o;
    o.x = excl; o.y = excl + v.x; o.z = o.y + v.y; o.w = o.z + v.z;
    ((int4*)(offs + base))[tid] = o;
    if (tid == 0 && b == 0) offs[n] = total;
}

// ---------------- atomic-free CSR fill: slot = offs[dst] + rank ----------------
__global__ void kfill_m(const int* __restrict__ src1, const int* __restrict__ dst1,
                        const int* __restrict__ ea, const int* __restrict__ rank1,
                        const int* __restrict__ offs1, int* __restrict__ col1,
                        const int* __restrict__ src2, const int* __restrict__ dst2,
                        const int* __restrict__ rank2, const int* __restrict__ offs2,
                        int* __restrict__ col2) {
    int b = blockIdx.x;
    if (b < 800) {
        int i = (b * 256 + threadIdx.x) * 4;
        int4 d4 = *(const int4*)(dst1 + i);
        int4 s4 = *(const int4*)(src1 + i);
        int4 r4 = *(const int4*)(rank1 + i);
        int4 e0 = *(const int4*)(ea + 2 * i);
        int4 e1 = *(const int4*)(ea + 2 * i + 4);
        col1[offs1[d4.x] + r4.x] = s4.x | ((e0.x * 3 + e0.y) << 16);
        col1[offs1[d4.y] + r4.y] = s4.y | ((e0.z * 3 + e0.w) << 16);
        col1[offs1[d4.z] + r4.z] = s4.z | ((e1.x * 3 + e1.y) << 16);
        col1[offs1[d4.w] + r4.w] = s4.w | ((e1.z * 3 + e1.w) << 16);
    } else {
        int i = ((b - 800) * 256 + threadIdx.x) * 4;
        int4 d4 = *(const int4*)(dst2 + i);
        int4 s4 = *(const int4*)(src2 + i);
        int4 r4 = *(const int4*)(rank2 + i);
        col2[offs2[d4.x] + r4.x] = s4.x;
        col2[offs2[d4.y] + r4.y] = s4.y;
        col2[offs2[d4.z] + r4.z] = s4.z;
        col2[offs2[d4.w] + r4.w] = s4.w;
    }
}

// ---------------- prep: embedding + weight prep + iso argmax ----------------
__global__ void kprepx(const float* __restrict__ x, const float* __restrict__ embW,
                       const float* __restrict__ embB, float* __restrict__ h,
                       const float* __restrict__ gW1, const float* __restrict__ gW2,
                       ushort_t* __restrict__ w1h, ushort_t* __restrict__ w1l,
                       ushort_t* __restrict__ w2h, ushort_t* __restrict__ w2l,
                       const float* __restrict__ iso, int* __restrict__ isoIdx) {
    int b = blockIdx.x;
    if (b < 12800) {
        int t = b * 256 + threadIdx.x;
        int n = t >> 6, d = t & 63;
        float acc = embB[d];
        const float* xr = x + n * 40;
#pragma unroll
        for (int k = 0; k < 40; ++k) acc = fmaf(xr[k], embW[k * 64 + d], acc);
        h[(size_t)n * 64 + d] = fmaxf(acc, 0.f);
    } else if (b < 12840) {
        int t = (b - 12800) * 256 + threadIdx.x;
        int lane = t & 63, frag = t >> 6;
        int c15 = lane & 15, q = lane >> 4;
        if (frag < 80) {
            int kt = frag & 1, nt = (frag >> 1) & 7, l = frag >> 4;
            const float* W = gW1 + l * 8192;
            ushort_t* oh = w1h + ((size_t)frag * 64 + lane) * 8;
            ushort_t* ol = w1l + ((size_t)frag * 64 + lane) * 8;
            int kb = kt * 32 + q * 8, colw = nt * 16 + c15;
#pragma unroll
            for (int j = 0; j < 8; ++j) {
                ushort_t hi, lo; bsplit(W[(kb + j) * 128 + colw], hi, lo);
                oh[j] = hi; ol[j] = lo;
            }
        } else if (frag < 160) {
            int f = frag - 80;
            int kt = f & 3, nt = (f >> 2) & 3, l = f >> 4;
            const float* W = gW2 + l * 8192;
            ushort_t* oh = w2h + ((size_t)f * 64 + lane) * 8;
            ushort_t* ol = w2l + ((size_t)f * 64 + lane) * 8;
            int kb = kt * 32 + q * 8, colw = nt * 16 + c15;
#pragma unroll
            for (int j = 0; j < 8; ++j) {
                ushort_t hi, lo; bsplit(W[(kb + j) * 64 + colw], hi, lo);
                oh[j] = hi; ol[j] = lo;
            }
        }
    } else {
        int j = (b - 12840) * 256 + threadIdx.x;
        const float4* r4 = (const float4*)(iso + (size_t)j * 36);
        int best = 0;
#pragma unroll
        for (int k = 0; k < 9; ++k) {
            float4 v = r4[k];
            if (v.x > 0.5f) best = 4 * k;
            if (v.y > 0.5f) best = 4 * k + 1;
            if (v.z > 0.5f) best = 4 * k + 2;
            if (v.w > 0.5f) best = 4 * k + 3;
        }
        isoIdx[j] = best;
    }
}

// ---------------- fused GIN layer: EDGE-BALANCED gather -> LDS -> MFMA MLP ----------------
// Block = 16 nodes (contiguous CSR range). Lane-groups stride the block's edge range
// uniformly; dst node via LDS edge->node map; accumulate via LDS float atomics.
// Removes the max-vs-mean degree tail at the MLP barrier.
template <int FOLD_BN>
__global__ __launch_bounds__(256) void kglayer(
    const float* __restrict__ hin, float* __restrict__ hout,
    const int* __restrict__ offs, const int* __restrict__ col,
    const float* __restrict__ e1, const float* __restrict__ e2,
    const ushort_t* __restrict__ w1h, const ushort_t* __restrict__ w1l,
    const ushort_t* __restrict__ w2h, const ushort_t* __restrict__ w2l,
    const float* __restrict__ b1, const float* __restrict__ b2,
    const float* __restrict__ pst, const float* __restrict__ gamma,
    const float* __restrict__ beta, float* __restrict__ pstout) {
    __shared__ float etab[13 * 64];
    __shared__ float sstat[128];
    __shared__ float sMLP[16 * 132];   // sA stride-68 aliases front; sH stride-132
    __shared__ int sOff[17];
    __shared__ short sMap[768];        // edge -> local node (T <= 768 with astronomical margin)
    float* sA = sMLP;
    float* sH = sMLP;
    int tid = threadIdx.x;
    for (int idx = tid; idx < 13 * 64; idx += 256) {
        int ci = idx >> 6, dd = idx & 63;
        etab[idx] = e1[(ci / 3) * 64 + dd] + e2[(ci % 3) * 64 + dd];
    }
    if (FOLD_BN && tid < 128) {
        float s = 0.f;
        const float* p = pst + tid;
#pragma unroll
        for (int i = 0; i < 32; ++i) s += p[i * 128];
        sstat[tid] = s;
    }
    if (tid < 17) sOff[tid] = offs[blockIdx.x * 16 + tid];
    __syncthreads();
    int lane = tid & 63, wv = tid >> 6;
    int c15 = lane & 15, q = lane >> 4;

    float sc0 = 1.f, sc1 = 1.f, sc2 = 1.f, sc3 = 1.f;
    float sh0 = 0.f, sh1 = 0.f, sh2 = 0.f, sh3 = 0.f;
    if (FOLD_BN) {
        int ch = 4 * c15;
        float mu, var;
        mu = sstat[ch] * (1.f / NN); var = sstat[64 + ch] * (1.f / NN) - mu * mu;
        sc0 = gamma[ch] * rsqrtf(var + 1e-5f); sh0 = beta[ch] - mu * sc0;
        mu = sstat[ch + 1] * (1.f / NN); var = sstat[65 + ch] * (1.f / NN) - mu * mu;
        sc1 = gamma[ch + 1] * rsqrtf(var + 1e-5f); sh1 = beta[ch + 1] - mu * sc1;
        mu = sstat[ch + 2] * (1.f / NN); var = sstat[66 + ch] * (1.f / NN) - mu * mu;
        sc2 = gamma[ch + 2] * rsqrtf(var + 1e-5f); sh2 = beta[ch + 2] - mu * sc2;
        mu = sstat[ch + 3] * (1.f / NN); var = sstat[67 + ch] * (1.f / NN) - mu * mu;
        sc3 = gamma[ch + 3] * rsqrtf(var + 1e-5f); sh3 = beta[ch + 3] - mu * sc3;
    }
    int S0 = sOff[0], S1 = sOff[16];
    int T = S1 - S0;

    // edge->node map (16 threads, one per node)
    if (tid < 16) {
        int lo = sOff[tid] - S0, hi = sOff[tid + 1] - S0;
        for (int e = lo; e < hi; ++e) sMap[e] = (short)tid;
    }
    // init sA = bnfold(self) + etab[12]   (thread t: node t>>4, channels 4*(t&15)..)
    {
        int j = tid >> 4;                  // c15 == tid & 15
        int n = blockIdx.x * 16 + j;
        float4 sx = *(const float4*)(hin + (size_t)n * 64 + 4 * c15);
        float a0 = sx.x, a1 = sx.y, a2 = sx.z, a3 = sx.w;
        if (FOLD_BN) {
            a0 = fmaxf(fmaf(a0, sc0, sh0), 0.f); a1 = fmaxf(fmaf(a1, sc1, sh1), 0.f);
            a2 = fmaxf(fmaf(a2, sc2, sh2), 0.f); a3 = fmaxf(fmaf(a3, sc3, sh3), 0.f);
        }
        float4 et = *(const float4*)(etab + 12 * 64 + 4 * c15);
        *(float4*)(sA + j * 68 + 4 * c15) =
            make_float4(a0 + et.x, a1 + et.y, a2 + et.z, a3 + et.w);
    }
    __syncthreads();

    // ---- edge-balanced accumulation: 16 lane-groups x 4 edges per iter (stride 64) ----
    int iters = (T + 63) >> 6;
    for (int it = 0; it < iters; ++it) {
        int eb = S0 + it * 64 + wv * 4 + q;
        int ee[4]; bool ok[4]; int vv[4];
#pragma unroll
        for (int j = 0; j < 4; ++j) {
            ee[j] = eb + j * 16;
            ok[j] = ee[j] < S1;
            vv[j] = ok[j] ? col[ee[j]] : 0;
        }
        float4 xv[4], tv[4]; int dn[4];
#pragma unroll
        for (int j = 0; j < 4; ++j) {
            int src = vv[j] & 0xFFFF;
            xv[j] = *(const float4*)(hin + (size_t)src * 64 + 4 * c15);
            tv[j] = *(const float4*)(etab + (vv[j] >> 16) * 64 + 4 * c15);
            dn[j] = ok[j] ? (int)sMap[ee[j] - S0] : 0;
        }
#pragma unroll
        for (int j = 0; j < 4; ++j) {
            if (ok[j]) {
                float v0 = xv[j].x, v1 = xv[j].y, v2 = xv[j].z, v3 = xv[j].w;
                if (FOLD_BN) {
                    v0 = fmaxf(fmaf(v0, sc0, sh0), 0.f);
                    v1 = fmaxf(fmaf(v1, sc1, sh1), 0.f);
                    v2 = fmaxf(fmaf(v2, sc2, sh2), 0.f);
                    v3 = fmaxf(fmaf(v3, sc3, sh3), 0.f);
                }
                float* ap = sA + dn[j] * 68 + 4 * c15;
                atomicAdd(ap + 0, v0 + tv[j].x);
                atomicAdd(ap + 1, v1 + tv[j].y);
                atomicAdd(ap + 2, v2 + tv[j].z);
                atomicAdd(ap + 3, v3 + tv[j].w);
            }
        }
    }
    __syncthreads();

    // ---- A-frags to regs (sA dies after next sync; sH aliases) ----
    bf16x8 ah[2], al[2];
#pragma unroll
    for (int kt = 0; kt < 2; ++kt) {
        const float* p = sA + c15 * 68 + kt * 32 + q * 8;
        float4 x0 = *(const float4*)p;
        float4 x1 = *(const float4*)(p + 4);
        float xs[8] = {x0.x, x0.y, x0.z, x0.w, x1.x, x1.y, x1.z, x1.w};
#pragma unroll
        for (int j = 0; j < 8; ++j) {
            ushort_t hi, lo; bsplit(xs[j], hi, lo);
            ah[kt][j] = (short)hi; al[kt][j] = (short)lo;
        }
    }
    __syncthreads();

    // ---- GEMM1: nt = 2wv+j ----
    f32x4 acc1[2];
#pragma unroll
    for (int j = 0; j < 2; ++j) { f32x4 z = {0.f, 0.f, 0.f, 0.f}; acc1[j] = z; }
#pragma unroll
    for (int kt = 0; kt < 2; ++kt) {
#pragma unroll
        for (int j = 0; j < 2; ++j) {
            int nt = 2 * wv + j;
            size_t fo = ((size_t)((nt * 2 + kt) * 64 + lane)) * 8;
            bf16x8 bh = *(const bf16x8*)(w1h + fo);
            bf16x8 bl = *(const bf16x8*)(w1l + fo);
            acc1[j] = __builtin_amdgcn_mfma_f32_16x16x32_bf16(ah[kt], bh, acc1[j], 0, 0, 0);
            acc1[j] = __builtin_amdgcn_mfma_f32_16x16x32_bf16(al[kt], bh, acc1[j], 0, 0, 0);
            acc1[j] = __builtin_amdgcn_mfma_f32_16x16x32_bf16(ah[kt], bl, acc1[j], 0, 0, 0);
        }
    }
#pragma unroll
    for (int j = 0; j < 2; ++j) {
        int nt = 2 * wv + j;
        float bias = b1[nt * 16 + c15];
#pragma unroll
        for (int rg = 0; rg < 4; ++rg)
            sH[(4 * q + rg) * 132 + nt * 16 + c15] = fmaxf(acc1[j][rg] + bias, 0.f);
    }
    __syncthreads();

    // ---- GEMM2: nt = wv ----
    f32x4 acc2 = {0.f, 0.f, 0.f, 0.f};
#pragma unroll
    for (int kt = 0; kt < 4; ++kt) {
        const float* p = sH + c15 * 132 + kt * 32 + q * 8;
        float4 x0 = *(const float4*)p;
        float4 x1 = *(const float4*)(p + 4);
        float xs[8] = {x0.x, x0.y, x0.z, x0.w, x1.x, x1.y, x1.z, x1.w};
        bf16x8 a2h, a2l;
#pragma unroll
        for (int j = 0; j < 8; ++j) {
            ushort_t hi, lo; bsplit(xs[j], hi, lo);
            a2h[j] = (short)hi; a2l[j] = (short)lo;
        }
        size_t fo = ((size_t)((wv * 4 + kt) * 64 + lane)) * 8;
        bf16x8 bh = *(const bf16x8*)(w2h + fo);
        bf16x8 bl = *(const bf16x8*)(w2l + fo);
        acc2 = __builtin_amdgcn_mfma_f32_16x16x32_bf16(a2h, bh, acc2, 0, 0, 0);
        acc2 = __builtin_amdgcn_mfma_f32_16x16x32_bf16(a2l, bh, acc2, 0, 0, 0);
        acc2 = __builtin_amdgcn_mfma_f32_16x16x32_bf16(a2h, bl, acc2, 0, 0, 0);
    }
    {
        float bias = b2[wv * 16 + c15];
        float s = 0.f, s2 = 0.f;
#pragma unroll
        for (int rg = 0; rg < 4; ++rg) {
            float v = acc2[rg] + bias;
            hout[(size_t)(blockIdx.x * 16 + 4 * q + rg) * 64 + wv * 16 + c15] = v;
            s += v; s2 += v * v;
        }
        s += __shfl_xor(s, 16, 64);  s += __shfl_xor(s, 32, 64);
        s2 += __shfl_xor(s2, 16, 64); s2 += __shfl_xor(s2, 32, 64);
        if (q == 0) {
            float* ps = pstout + (size_t)(blockIdx.x & 31) * 128;
            atomicAdd(&ps[wv * 16 + c15], s);
            atomicAdd(&ps[64 + wv * 16 + c15], s2);
        }
    }
}

// ---------------- 2-set pooling (raw, no BN) ----------------
__global__ void kpool2(const float* __restrict__ h2, const int* __restrict__ a0,
                       float* __restrict__ xp) {
    int t = blockIdx.x * 256 + threadIdx.x;
    int j = t >> 4, c = t & 15;
    int na = a0[2 * j], nb = a0[2 * j + 1];
    float4 va = *(const float4*)(h2 + (size_t)na * 64 + 4 * c);
    float4 vb = *(const float4*)(h2 + (size_t)nb * 64 + 4 * c);
    float4 o = make_float4(0.5f * (va.x + vb.x), 0.5f * (va.y + vb.y),
                           0.5f * (va.z + vb.z), 0.5f * (va.w + vb.w));
    *(float4*)(xp + (size_t)j * 64 + 4 * c) = o;
}

// ---------------- GraphConv GEMMs; FIRST applies final-layer BN during staging + iso rows ----------------
template <int FIRST>
__global__ __launch_bounds__(256) void kgcmm(const float* __restrict__ X,
                                             const float* __restrict__ Wrel,
                                             const float* __restrict__ Wroot,
                                             const float* __restrict__ WrelIso,
                                             const float* __restrict__ WrootIso,
                                             const int* __restrict__ isoIdx,
                                             float* __restrict__ Yrel,
                                             float* __restrict__ Yroot,
                                             const float* __restrict__ pst,
                                             const float* __restrict__ g4,
                                             const float* __restrict__ b4) {
    __shared__ float sX[64 * 65];
    __shared__ float sR[64 * 64];
    __shared__ float sT[64 * 64];
    __shared__ float sstat[128];
    __shared__ float sSC[64], sSH[64];
    int tid = threadIdx.x, blk = blockIdx.x;
    if (FIRST && tid < 128) {
        float s = 0.f;
        const float* p = pst + tid;
#pragma unroll
        for (int i = 0; i < 32; ++i) s += p[i * 128];
        sstat[tid] = s;
    }
#pragma unroll
    for (int i = tid; i < 1024; i += 256) {
        ((float4*)sR)[i] = ((const float4*)Wrel)[i];
        ((float4*)sT)[i] = ((const float4*)Wroot)[i];
    }
    __syncthreads();
    if (FIRST && tid < 64) {
        float mu = sstat[tid] * (1.f / NN);
        float var = sstat[64 + tid] * (1.f / NN) - mu * mu;
        float sc = g4[tid] * rsqrtf(var + 1e-5f);
        sSC[tid] = sc;
        sSH[tid] = b4[tid] - mu * sc;
    }
    __syncthreads();
    const float4* x4 = (const float4*)(X + (size_t)blk * 4096);
#pragma unroll
    for (int i = tid; i < 1024; i += 256) {
        float4 v = x4[i];
        int row = i >> 4, c = (i & 15) << 2;
        if (FIRST) {
            v.x = fmaf(v.x, sSC[c], sSH[c]);
            v.y = fmaf(v.y, sSC[c + 1], sSH[c + 1]);
            v.z = fmaf(v.z, sSC[c + 2], sSH[c + 2]);
            v.w = fmaf(v.w, sSC[c + 3], sSH[c + 3]);
        }
        float* p = sX + row * 65 + c;
        p[0] = v.x; p[1] = v.y; p[2] = v.z; p[3] = v.w;
    }
    __syncthreads();
    int tm = tid >> 4, tn = tid & 15;
    float aR[4][4], aT[4][4];
#pragma unroll
    for (int r = 0; r < 4; ++r)
#pragma unroll
        for (int c = 0; c < 4; ++c) { aR[r][c] = 0.f; aT[r][c] = 0.f; }
    const float* xrow = sX + tm * 4 * 65;
#pragma unroll 4
    for (int k = 0; k < 64; ++k) {
        float a0 = xrow[k], a1 = xrow[65 + k], a2 = xrow[130 + k], a3 = xrow[195 + k];
        float4 br = *(const float4*)(sR + k * 64 + tn * 4);
        float4 bt = *(const float4*)(sT + k * 64 + tn * 4);
        float rb[4] = {br.x, br.y, br.z, br.w};
        float tb[4] = {bt.x, bt.y, bt.z, bt.w};
#pragma unroll
        for (int c = 0; c < 4; ++c) {
            aR[0][c] = fmaf(a0, rb[c], aR[0][c]); aR[1][c] = fmaf(a1, rb[c], aR[1][c]);
            aR[2][c] = fmaf(a2, rb[c], aR[2][c]); aR[3][c] = fmaf(a3, rb[c], aR[3][c]);
            aT[0][c] = fmaf(a0, tb[c], aT[0][c]); aT[1][c] = fmaf(a1, tb[c], aT[1][c]);
            aT[2][c] = fmaf(a2, tb[c], aT[2][c]); aT[3][c] = fmaf(a3, tb[c], aT[3][c]);
        }
    }
#pragma unroll
    for (int r = 0; r < 4; ++r) {
        int row = blk * 64 + tm * 4 + r;
        float4 vr = make_float4(aR[r][0], aR[r][1], aR[r][2], aR[r][3]);
        float4 vt = make_float4(aT[r][0], aT[r][1], aT[r][2], aT[r][3]);
        if (FIRST) {
            int ii = isoIdx[row];
            float4 er = *(const float4*)(WrelIso + (size_t)ii * 64 + tn * 4);
            float4 et = *(const float4*)(WrootIso + (size_t)ii * 64 + tn * 4);
            vr.x += er.x; vr.y += er.y; vr.z += er.z; vr.w += er.w;
            vt.x += et.x; vt.y += et.y; vt.z += et.z; vt.w += et.w;
        }
        *(float4*)(Yrel + (size_t)row * 64 + tn * 4) = vr;
        *(float4*)(Yroot + (size_t)row * 64 + tn * 4) = vt;
    }
}

// ---------------- GraphConv gather ----------------
__global__ void kgather2(const float* __restrict__ yrel, const float* __restrict__ yroot,
                         const float* __restrict__ brel, const int* __restrict__ offs,
                         const int* __restrict__ col, float* __restrict__ out) {
    int t = blockIdx.x * 256 + threadIdx.x;
    int j = t >> 4, c = t & 15;
    int s0 = offs[j], s1 = offs[j + 1];
    float4 rt = *(const float4*)(yroot + (size_t)j * 64 + 4 * c);
    float4 bb = *(const float4*)(brel + 4 * c);
    float a0 = rt.x + bb.x, a1 = rt.y + bb.y, a2 = rt.z + bb.z, a3 = rt.w + bb.w;
    int e = s0;
    for (; e + 4 <= s1; e += 4) {
        int v0 = col[e], v1 = col[e + 1], v2 = col[e + 2], v3 = col[e + 3];
        float4 x0 = *(const float4*)(yrel + (size_t)v0 * 64 + 4 * c);
        float4 x1 = *(const float4*)(yrel + (size_t)v1 * 64 + 4 * c);
        float4 x2 = *(const float4*)(yrel + (size_t)v2 * 64 + 4 * c);
        float4 x3 = *(const float4*)(yrel + (size_t)v3 * 64 + 4 * c);
        a0 += (x0.x + x1.x) + (x2.x + x3.x);
        a1 += (x0.y + x1.y) + (x2.y + x3.y);
        a2 += (x0.z + x1.z) + (x2.z + x3.z);
        a3 += (x0.w + x1.w) + (x2.w + x3.w);
    }
    for (; e < s1; ++e) {
        float4 x = *(const float4*)(yrel + (size_t)col[e] * 64 + 4 * c);
        a0 += x.x; a1 += x.y; a2 += x.z; a3 += x.w;
    }
    *(float4*)(out + (size_t)j * 64 + 4 * c) =
        make_float4(fmaxf(a0, 0.f), fmaxf(a1, 0.f), fmaxf(a2, 0.f), fmaxf(a3, 0.f));
}

// ---------------- per-graph mean pools (x1 gets final BN affine on the mean) ----------------
__global__ void kpoolg(const float* __restrict__ h2, const float* __restrict__ xp2,
                       const float* __restrict__ pst, const float* __restrict__ g4,
                       const float* __restrict__ b4, float* __restrict__ m) {
    __shared__ float sstat[128];
    __shared__ float red[4][64];
    int g = blockIdx.x, tid = threadIdx.x;
    if (tid < 128) {
        float s = 0.f;
        const float* p = pst + tid;
#pragma unroll
        for (int i = 0; i < 32; ++i) s += p[i * 128];
        sstat[tid] = s;
    }
    int wid = tid >> 6, d = tid & 63;
    float s1 = 0.f;
    for (int i = wid; i < 200; i += 4) s1 += h2[((size_t)g * 200 + i) * 64 + d];
    red[wid][d] = s1;
    __syncthreads();
    if (wid == 0) {
        float mean = (red[0][d] + red[1][d] + red[2][d] + red[3][d]) * (1.f / 200.f);
        float mu = sstat[d] * (1.f / NN);
        float var = sstat[64 + d] * (1.f / NN) - mu * mu;
        float sc = g4[d] * rsqrtf(var + 1e-5f);
        m[g * 128 + d] = fmaf(mean, sc, b4[d] - mu * sc);
    }
    __syncthreads();
    float s2 = 0.f;
    for (int i = wid; i < 400; i += 4) s2 += xp2[((size_t)g * 400 + i) * 64 + d];
    red[wid][d] = s2;
    __syncthreads();
    if (wid == 0) m[g * 128 + 64 + d] = (red[0][d] + red[1][d] + red[2][d] + red[3][d]) * (1.f / 400.f);
}

// ---------------- readout MLP ----------------
__global__ void kread(const float* __restrict__ m, const float* __restrict__ W0,
                      const float* __restrict__ b0, const float* __restrict__ W1,
                      const float* __restrict__ b1, const float* __restrict__ W2,
                      const float* __restrict__ b2, const float* __restrict__ lw,
                      const float* __restrict__ lb, float* __restrict__ out) {
    __shared__ float s0[64], s1[32], s2[16];
    int g = blockIdx.x, d = threadIdx.x;
    const float* mr = m + g * 128;
    float t = b0[d];
    for (int k = 0; k < 128; ++k) t = fmaf(mr[k], W0[k * 64 + d], t);
    s0[d] = fmaxf(t, 0.f);
    __syncthreads();
    if (d < 32) {
        float u = b1[d];
        for (int k = 0; k < 64; ++k) u = fmaf(s0[k], W1[k * 32 + d], u);
        s1[d] = fmaxf(u, 0.f);
    }
    __syncthreads();
    if (d < 16) {
        float u = b2[d];
        for (int k = 0; k < 32; ++k) u = fmaf(s1[k], W2[k * 16 + d], u);
        s2[d] = fmaxf(u, 0.f);
    }
    __syncthreads();
    if (d == 0) {
        float u = lb[0];
        for (int k = 0; k < 16; ++k) u = fmaf(s2[k], lw[k], u);
        out[g] = u;
    }
}

// ---------------- host ----------------
extern "C" void kernel_launch(void* const* d_in, const int* in_sizes, int n_in,
                              void* d_out, int out_size, void* d_ws, size_t ws_size,
                              hipStream_t stream) {
    if (ws_size < WS_NEEDED) return;

    const float* x    = (const float*)d_in[0];
    const int*   ei   = (const int*)d_in[1];
    const int*   ea   = (const int*)d_in[2];
    const float* iso  = (const float*)d_in[4];
    const int*   ei2  = (const int*)d_in[5];
    const int*   ai2  = (const int*)d_in[6];
    const float* embW = (const float*)d_in[8];
    const float* embB = (const float*)d_in[9];
    const float* gW1  = (const float*)d_in[10];
    const float* gB1  = (const float*)d_in[11];
    const float* gW2  = (const float*)d_in[12];
    const float* gB2  = (const float*)d_in[13];
    const float* ee1  = (const float*)d_in[14];
    const float* ee2  = (const float*)d_in[15];
    const float* bng  = (const float*)d_in[16];
    const float* bnb  = (const float*)d_in[17];
    const float* i1rW = (const float*)d_in[18];
    const float* i1rB = (const float*)d_in[19];
    const float* i1tW = (const float*)d_in[20];
    const float* i2rW = (const float*)d_in[21];
    const float* i2rB = (const float*)d_in[22];
    const float* i2tW = (const float*)d_in[23];
    const float* roW0 = (const float*)d_in[24];
    const float* roB0 = (const float*)d_in[25];
    const float* roW1 = (const float*)d_in[26];
    const float* roB1 = (const float*)d_in[27];
    const float* roW2 = (const float*)d_in[28];
    const float* roB2 = (const float*)d_in[29];
    const float* lW   = (const float*)d_in[30];
    const float* lB   = (const float*)d_in[31];
    float* out = (float*)d_out;

    char* ws = (char*)d_ws;
    float* h      = (float*)(ws + OFF_H);
    float* hB     = (float*)(ws + OFF_AGG);    // ping-pong buffer B
    float* hA     = (float*)(ws + OFF_H2);     // ping-pong buffer A; final h2
    float* h2     = hA;
    float* xp     = (float*)(ws + OFF_XP);
    float* yrel   = (float*)(ws + OFF_H);      // spans h+hB (both dead post-GIN)
    float* yroot  = (float*)(ws + OFF_YROOT);
    int* offs1    = (int*)(ws + OFF_OFFS1);
    int* col1     = (int*)(ws + OFF_COL1);
    int* offs2    = (int*)(ws + OFF_OFFS2);
    int* col2     = (int*)(ws + OFF_COL2);
    int* cnt1     = (int*)(ws + OFF_CNT1);
    int* cnt2     = (int*)(ws + OFF_CNT2);
    int* isoIdx   = (int*)(ws + OFF_ISO);
    float* mbuf   = (float*)(ws + OFF_M);
    int* bsum1    = (int*)(ws + OFF_M);
    int* boffs1   = (int*)(ws + OFF_M + 256);
    int* bsum2    = (int*)(ws + OFF_M + 512);
    int* boffs2   = (int*)(ws + OFF_M + 1024);
    ushort_t* w1h = (ushort_t*)(ws + OFF_YROOT);
    ushort_t* w1l = (ushort_t*)(ws + OFF_YROOT + 81920);
    ushort_t* w2h = (ushort_t*)(ws + OFF_YROOT + 163840);
    ushort_t* w2l = (ushort_t*)(ws + OFF_YROOT + 245760);
    float* pstat2 = (float*)(ws + OFF_CUR1);   // zeroed by memset each launch
    int* rank1    = (int*)(ws + OFF_XP);       // xp dead until kpool2
    int* rank2    = (int*)(ws + OFF_XP + (size_t)EE * 4);

    const int* src1 = ei;
    const int* dst1 = ei + EE;
    const int* src2 = ei2;
    const int* dst2 = ei2 + EE2;
    const int* a0   = ai2;

    hipMemsetAsync(ws + OFF_CNT1, 0, ZERO_BYTES, stream);

    // CSR build (R11 structure: rank capture + atomic-free fill)
    khist_m<<<1200, 256, 0, stream>>>(dst1, dst2, cnt1, cnt2, rank1, rank2);
    kprepx<<<13240, 256, 0, stream>>>(x, embW, embB, h, gW1, gW2,
                                      w1h, w1l, w2h, w2l, iso, isoIdx);
    kreduce_m<<<150, 256, 0, stream>>>(cnt1, cnt2, bsum1, bsum2);
    kscan_small_m<<<2, 128, 0, stream>>>(bsum1, bsum2, boffs1, boffs2);
    kscan_apply_m<<<150, 256, 0, stream>>>(cnt1, cnt2, boffs1, boffs2, offs1, offs2);
    kfill_m<<<1200, 256, 0, stream>>>(src1, dst1, ea, rank1, offs1, col1,
                                      src2, dst2, rank2, offs2, col2);

    // GIN layers: fused edge-balanced gather+MLP, h ping-pong (layer 4 lands in hA = h2)
    for (int l = 0; l < LL; ++l) {
        const float* hin = (l == 0) ? h : ((l & 1) ? hA : hB);
        float* hout = (l & 1) ? hB : hA;
        if (l == 0) {
            kglayer<0><<<NN / 16, 256, 0, stream>>>(
                hin, hout, offs1, col1, ee1, ee2,
                w1h, w1l, w2h, w2l, gB1, gB2,
                nullptr, nullptr, nullptr, pstat2);
        } else {
            kglayer<1><<<NN / 16, 256, 0, stream>>>(
                hin, hout, offs1, col1, ee1 + l * 384, ee2 + l * 192,
                w1h + (size_t)l * 8192, w1l + (size_t)l * 8192,
                w2h + (size_t)l * 8192, w2l + (size_t)l * 8192,
                gB1 + l * 128, gB2 + l * 64,
                pstat2 + (size_t)(l - 1) * 4096,
                bng + (l - 1) * 64, bnb + (l - 1) * 64,
                pstat2 + (size_t)l * 4096);
        }
    }

    // 2-set branch (final-layer BN folded into kgcmm<1> staging and kpoolg mean)
    kpool2<<<NN2 * 16 / 256, 256, 0, stream>>>(h2, a0, xp);
    kgcmm<1><<<NN2 / 64, 256, 0, stream>>>(xp, i1rW, i1tW, i1rW + 64 * 64,
                                           i1tW + 64 * 64, isoIdx, yrel, yroot,
                                           pstat2 + (size_t)4 * 4096,
                                           bng + 4 * 64, bnb + 4 * 64);
    kgather2<<<NN2 * 16 / 256, 256, 0, stream>>>(yrel, yroot, i1rB, offs2, col2, xp);
    kgcmm<0><<<NN2 / 64, 256, 0, stream>>>(xp, i2rW, i2tW, nullptr, nullptr,
                                           nullptr, yrel, yroot,
                                           nullptr, nullptr, nullptr);
    kgather2<<<NN2 * 16 / 256, 256, 0, stream>>>(yrel, yroot, i2rB, offs2, col2, xp);

    // pools + readout
    kpoolg<<<GG, 256, 0, stream>>>(h2, xp, pstat2 + (size_t)4 * 4096,
                                   bng + 4 * 64, bnb + 4 * 64, mbuf);
    kread<<<GG, 64, 0, stream>>>(mbuf, roW0, roB0, roW1, roB1, roW2, roB2, lW, lB, out);
}

// Round 17
// 679.054 us; speedup vs baseline: 2.7345x; 2.7345x over previous
//
#include <hip/hip_runtime.h>

#define NN   51200
#define EE   819200
#define GG   256
#define NN2  102400
#define AA   204800
#define EE2  409600
#define DD   64
#define LL   5

typedef __attribute__((ext_vector_type(8))) short bf16x8;
typedef __attribute__((ext_vector_type(4))) float f32x4;
typedef unsigned short ushort_t;

// ---------------- workspace layout (bytes) ----------------
#define OFF_H      ((size_t)0)          // emb h; post-GIN: yrel spans OFF_H..OFF_H2
#define OFF_AGG    ((size_t)13107200)   // GIN: h ping-pong buffer B
#define OFF_H2     ((size_t)26214400)   // GIN: buffer A; layer-4 output = h2 (alive to kpoolg)
#define OFF_XP     ((size_t)39321600)   // front 4.9 MB: rank1/rank2 during CSR build
#define OFF_YROOT  ((size_t)65536000)   // prepped bf16 weights during GIN; yroot after
#define OFF_OFFS1  ((size_t)91750400)
#define OFF_COL1   ((size_t)91955216)
#define OFF_OFFS2  ((size_t)95232016)
#define OFF_COL2   ((size_t)95641632)
#define OFF_CNT1   ((size_t)97280032)   // zeroed region starts here
#define OFF_CUR1   ((size_t)97484832)   // pstat2[5][32][128] during GIN (zeroed by memset)
#define OFF_CNT2   ((size_t)97689632)
#define OFF_CUR2   ((size_t)98099232)
#define OFF_STATS  ((size_t)98508832)
#define ZERO_BYTES ((size_t)1231360)
#define OFF_ISO    ((size_t)98511392)
#define OFF_M      ((size_t)98920992)
#define WS_NEEDED  ((size_t)99052064)

__device__ __forceinline__ int waveInclScan(int v, int lane) {
#pragma unroll
    for (int off = 1; off < 64; off <<= 1) {
        int t = __shfl_up(v, off, 64);
        if (lane >= off) v += t;
    }
    return v;
}

// ---------------- split-bf16 helpers ----------------
__device__ __forceinline__ void bsplit(float x, ushort_t& hi, ushort_t& lo) {
    union { float f; unsigned u; } a; a.f = x;
    unsigned hb = (a.u + 0x7FFFu + ((a.u >> 16) & 1u)) >> 16;   // RNE to bf16
    union { unsigned u; float f; } h; h.u = hb << 16;
    float r = x - h.f;
    union { float f; unsigned u; } b; b.f = r;
    unsigned lb = (b.u + 0x7FFFu + ((b.u >> 16) & 1u)) >> 16;
    hi = (ushort_t)hb; lo = (ushort_t)lb;
}

// ---------------- CSR histogram + rank capture (R11 structure — measured best) ----------------
__global__ void khist_m(const int* __restrict__ dst1, const int* __restrict__ dst2,
                        int* __restrict__ cnt1, int* __restrict__ cnt2,
                        int* __restrict__ rank1, int* __restrict__ rank2) {
    int b = blockIdx.x;
    if (b < 800) {
        int i = (b * 256 + threadIdx.x) * 4;
        int4 d = *(const int4*)(dst1 + i);
        int4 r;
        r.x = atomicAdd(&cnt1[d.x], 1);
        r.y = atomicAdd(&cnt1[d.y], 1);
        r.z = atomicAdd(&cnt1[d.z], 1);
        r.w = atomicAdd(&cnt1[d.w], 1);
        *(int4*)(rank1 + i) = r;
    } else {
        int i = ((b - 800) * 256 + threadIdx.x) * 4;
        int4 d = *(const int4*)(dst2 + i);
        int4 r;
        r.x = atomicAdd(&cnt2[d.x], 1);
        r.y = atomicAdd(&cnt2[d.y], 1);
        r.z = atomicAdd(&cnt2[d.z], 1);
        r.w = atomicAdd(&cnt2[d.w], 1);
        *(int4*)(rank2 + i) = r;
    }
}

__global__ void kreduce_m(const int* __restrict__ cnt1, const int* __restrict__ cnt2,
                          int* __restrict__ bsum1, int* __restrict__ bsum2) {
    __shared__ int wsr[4];
    int b = blockIdx.x;
    const int* cnt; int* bsum;
    if (b < 50) { cnt = cnt1; bsum = bsum1; }
    else { b -= 50; cnt = cnt2; bsum = bsum2; }
    int tid = threadIdx.x, lane = tid & 63, wid = tid >> 6;
    int4 v = ((const int4*)(cnt + (size_t)b * 1024))[tid];
    int s = v.x + v.y + v.z + v.w;
#pragma unroll
    for (int off = 32; off; off >>= 1) s += __shfl_down(s, off, 64);
    if (lane == 0) wsr[wid] = s;
    __syncthreads();
    if (tid == 0) bsum[b] = wsr[0] + wsr[1] + wsr[2] + wsr[3];
}

__global__ void kscan_small_m(const int* __restrict__ bsum1, const int* __restrict__ bsum2,
                              int* __restrict__ boffs1, int* __restrict__ boffs2) {
    __shared__ int w0s;
    const int* bsum = blockIdx.x ? bsum2 : bsum1;
    int* boffs = blockIdx.x ? boffs2 : boffs1;
    int nb = blockIdx.x ? 100 : 50;
    int tid = threadIdx.x, lane = tid & 63, wid = tid >> 6;
    int v = (tid < nb) ? bsum[tid] : 0;
    int incl = waveInclScan(v, lane);
    if (tid == 63) w0s = incl;
    __syncthreads();
    int excl = incl - v + (wid ? w0s : 0);
    if (tid < nb) boffs[tid] = excl;
}

__global__ void kscan_apply_m(const int* __restrict__ cnt1, const int* __restrict__ cnt2,
                              const int* __restrict__ boffs1, const int* __restrict__ boffs2,
                              int* __restrict__ offs1, int* __restrict__ offs2) {
    __shared__ int wsum[4];
    int b = blockIdx.x;
    const int* cnt; const int* boffs; int* offs; int n, total;
    if (b < 50) { cnt = cnt1; boffs = boffs1; offs = offs1; n = NN; total = EE; }
    else { b -= 50; cnt = cnt2; boffs = boffs2; offs = offs2; n = NN2; total = EE2; }
    int tid = threadIdx.x, lane = tid & 63, wid = tid >> 6;
    size_t base = (size_t)b * 1024;
    int4 v = ((const int4*)(cnt + base))[tid];
    int s = v.x + v.y + v.z + v.w;
    int incl = waveInclScan(s, lane);
    if (lane == 63) wsum[wid] = incl;
    __syncthreads();
    int woff = boffs[b];
#pragma unroll
    for (int w = 0; w < 3; ++w) woff += (w < wid) ? wsum[w] : 0;
    int excl = woff + incl - s;
    int4 o;
    o.x = excl; o.y = excl + v.x; o.z = o.y + v.y; o.w = o.z + v.z;
    ((int4*)(offs + base))[tid] = o;
    if (tid == 0 && b == 0) offs[n] = total;
}

// ---------------- atomic-free CSR fill: slot = offs[dst] + rank ----------------
__global__ void kfill_m(const int* __restrict__ src1, const int* __restrict__ dst1,
                        const int* __restrict__ ea, const int* __restrict__ rank1,
                        const int* __restrict__ offs1, int* __restrict__ col1,
                        const int* __restrict__ src2, const int* __restrict__ dst2,
                        const int* __restrict__ rank2, const int* __restrict__ offs2,
                        int* __restrict__ col2) {
    int b = blockIdx.x;
    if (b < 800) {
        int i = (b * 256 + threadIdx.x) * 4;
        int4 d4 = *(const int4*)(dst1 + i);
        int4 s4 = *(const int4*)(src1 + i);
        int4 r4 = *(const int4*)(rank1 + i);
        int4 e0 = *(const int4*)(ea + 2 * i);
        int4 e1 = *(const int4*)(ea + 2 * i + 4);
        col1[offs1[d4.x] + r4.x] = s4.x | ((e0.x * 3 + e0.y) << 16);
        col1[offs1[d4.y] + r4.y] = s4.y | ((e0.z * 3 + e0.w) << 16);
        col1[offs1[d4.z] + r4.z] = s4.z | ((e1.x * 3 + e1.y) << 16);
        col1[offs1[d4.w] + r4.w] = s4.w | ((e1.z * 3 + e1.w) << 16);
    } else {
        int i = ((b - 800) * 256 + threadIdx.x) * 4;
        int4 d4 = *(const int4*)(dst2 + i);
        int4 s4 = *(const int4*)(src2 + i);
        int4 r4 = *(const int4*)(rank2 + i);
        col2[offs2[d4.x] + r4.x] = s4.x;
        col2[offs2[d4.y] + r4.y] = s4.y;
        col2[offs2[d4.z] + r4.z] = s4.z;
        col2[offs2[d4.w] + r4.w] = s4.w;
    }
}

// ---------------- prep: embedding + weight prep + iso argmax ----------------
__global__ void kprepx(const float* __restrict__ x, const float* __restrict__ embW,
                       const float* __restrict__ embB, float* __restrict__ h,
                       const float* __restrict__ gW1, const float* __restrict__ gW2,
                       ushort_t* __restrict__ w1h, ushort_t* __restrict__ w1l,
                       ushort_t* __restrict__ w2h, ushort_t* __restrict__ w2l,
                       const float* __restrict__ iso, int* __restrict__ isoIdx) {
    int b = blockIdx.x;
    if (b < 12800) {
        int t = b * 256 + threadIdx.x;
        int n = t >> 6, d = t & 63;
        float acc = embB[d];
        const float* xr = x + n * 40;
#pragma unroll
        for (int k = 0; k < 40; ++k) acc = fmaf(xr[k], embW[k * 64 + d], acc);
        h[(size_t)n * 64 + d] = fmaxf(acc, 0.f);
    } else if (b < 12840) {
        int t = (b - 12800) * 256 + threadIdx.x;
        int lane = t & 63, frag = t >> 6;
        int c15 = lane & 15, q = lane >> 4;
        if (frag < 80) {
            int kt = frag & 1, nt = (frag >> 1) & 7, l = frag >> 4;
            const float* W = gW1 + l * 8192;
            ushort_t* oh = w1h + ((size_t)frag * 64 + lane) * 8;
            ushort_t* ol = w1l + ((size_t)frag * 64 + lane) * 8;
            int kb = kt * 32 + q * 8, colw = nt * 16 + c15;
#pragma unroll
            for (int j = 0; j < 8; ++j) {
                ushort_t hi, lo; bsplit(W[(kb + j) * 128 + colw], hi, lo);
                oh[j] = hi; ol[j] = lo;
            }
        } else if (frag < 160) {
            int f = frag - 80;
            int kt = f & 3, nt = (f >> 2) & 3, l = f >> 4;
            const float* W = gW2 + l * 8192;
            ushort_t* oh = w2h + ((size_t)f * 64 + lane) * 8;
            ushort_t* ol = w2l + ((size_t)f * 64 + lane) * 8;
            int kb = kt * 32 + q * 8, colw = nt * 16 + c15;
#pragma unroll
            for (int j = 0; j < 8; ++j) {
                ushort_t hi, lo; bsplit(W[(kb + j) * 64 + colw], hi, lo);
                oh[j] = hi; ol[j] = lo;
            }
        }
    } else {
        int j = (b - 12840) * 256 + threadIdx.x;
        const float4* r4 = (const float4*)(iso + (size_t)j * 36);
        int best = 0;
#pragma unroll
        for (int k = 0; k < 9; ++k) {
            float4 v = r4[k];
            if (v.x > 0.5f) best = 4 * k;
            if (v.y > 0.5f) best = 4 * k + 1;
            if (v.z > 0.5f) best = 4 * k + 2;
            if (v.w > 0.5f) best = 4 * k + 3;
        }
        isoIdx[j] = best;
    }
}

// ---------------- fused GIN layer: gather(16 nodes) -> LDS -> MFMA MLP -> hout + stats ----------------
// 256 threads, 4 waves. Wave wv gathers nodes wv*4+q (q=lane>>4), 16 lanes/node (float4 ch).
// MLP: GEMM1 waves split N (nt=2wv,2wv+1), GEMM2 nt=wv. Split-bf16 fp32 emulation.
template <int FOLD_BN>
__global__ __launch_bounds__(256) void kglayer(
    const float* __restrict__ hin, float* __restrict__ hout,
    const int* __restrict__ offs, const int* __restrict__ col,
    const float* __restrict__ e1, const float* __restrict__ e2,
    const ushort_t* __restrict__ w1h, const ushort_t* __restrict__ w1l,
    const ushort_t* __restrict__ w2h, const ushort_t* __restrict__ w2l,
    const float* __restrict__ b1, const float* __restrict__ b2,
    const float* __restrict__ pst, const float* __restrict__ gamma,
    const float* __restrict__ beta, float* __restrict__ pstout) {
    __shared__ float etab[13 * 64];
    __shared__ float sstat[128];
    __shared__ float sMLP[16 * 132];   // sA stride-68 aliases front; sH stride-132
    float* sA = sMLP;
    float* sH = sMLP;
    int tid = threadIdx.x;
    for (int idx = tid; idx < 13 * 64; idx += 256) {
        int ci = idx >> 6, dd = idx & 63;
        etab[idx] = e1[(ci / 3) * 64 + dd] + e2[(ci % 3) * 64 + dd];
    }
    if (FOLD_BN && tid < 128) {
        float s = 0.f;
        const float* p = pst + tid;
#pragma unroll
        for (int i = 0; i < 32; ++i) s += p[i * 128];
        sstat[tid] = s;
    }
    __syncthreads();
    int lane = tid & 63, wv = tid >> 6;
    int c15 = lane & 15, q = lane >> 4;

    float sc0 = 1.f, sc1 = 1.f, sc2 = 1.f, sc3 = 1.f;
    float sh0 = 0.f, sh1 = 0.f, sh2 = 0.f, sh3 = 0.f;
    if (FOLD_BN) {
        int ch = 4 * c15;
        float mu, var;
        mu = sstat[ch] * (1.f / NN); var = sstat[64 + ch] * (1.f / NN) - mu * mu;
        sc0 = gamma[ch] * rsqrtf(var + 1e-5f); sh0 = beta[ch] - mu * sc0;
        mu = sstat[ch + 1] * (1.f / NN); var = sstat[65 + ch] * (1.f / NN) - mu * mu;
        sc1 = gamma[ch + 1] * rsqrtf(var + 1e-5f); sh1 = beta[ch + 1] - mu * sc1;
        mu = sstat[ch + 2] * (1.f / NN); var = sstat[66 + ch] * (1.f / NN) - mu * mu;
        sc2 = gamma[ch + 2] * rsqrtf(var + 1e-5f); sh2 = beta[ch + 2] - mu * sc2;
        mu = sstat[ch + 3] * (1.f / NN); var = sstat[67 + ch] * (1.f / NN) - mu * mu;
        sc3 = gamma[ch + 3] * rsqrtf(var + 1e-5f); sh3 = beta[ch + 3] - mu * sc3;
    }

    // ---- gather node n into sA ----
    {
        int n = blockIdx.x * 16 + wv * 4 + q;
        int s0 = offs[n], s1 = offs[n + 1];
        float4 sx = *(const float4*)(hin + (size_t)n * 64 + 4 * c15);
        float a0 = sx.x, a1 = sx.y, a2 = sx.z, a3 = sx.w;
        if (FOLD_BN) {
            a0 = fmaxf(fmaf(a0, sc0, sh0), 0.f); a1 = fmaxf(fmaf(a1, sc1, sh1), 0.f);
            a2 = fmaxf(fmaf(a2, sc2, sh2), 0.f); a3 = fmaxf(fmaf(a3, sc3, sh3), 0.f);
        }
        float4 et = *(const float4*)(etab + 12 * 64 + 4 * c15);
        a0 += et.x; a1 += et.y; a2 += et.z; a3 += et.w;
        int e = s0;
        for (; e + 8 <= s1; e += 8) {
            int vv[8];
#pragma unroll
            for (int j = 0; j < 8; ++j) vv[j] = col[e + j];
            float4 xv[8], tv[8];
#pragma unroll
            for (int j = 0; j < 8; ++j) {
                xv[j] = *(const float4*)(hin + (size_t)(vv[j] & 0xFFFF) * 64 + 4 * c15);
                tv[j] = *(const float4*)(etab + (vv[j] >> 16) * 64 + 4 * c15);
            }
#pragma unroll
            for (int j = 0; j < 8; ++j) {
                if (FOLD_BN) {
                    xv[j].x = fmaxf(fmaf(xv[j].x, sc0, sh0), 0.f);
                    xv[j].y = fmaxf(fmaf(xv[j].y, sc1, sh1), 0.f);
                    xv[j].z = fmaxf(fmaf(xv[j].z, sc2, sh2), 0.f);
                    xv[j].w = fmaxf(fmaf(xv[j].w, sc3, sh3), 0.f);
                }
                a0 += xv[j].x + tv[j].x;
                a1 += xv[j].y + tv[j].y;
                a2 += xv[j].z + tv[j].z;
                a3 += xv[j].w + tv[j].w;
            }
        }
        for (; e < s1; ++e) {
            int v = col[e];
            float4 xv = *(const float4*)(hin + (size_t)(v & 0xFFFF) * 64 + 4 * c15);
            float4 tv = *(const float4*)(etab + (v >> 16) * 64 + 4 * c15);
            if (FOLD_BN) {
                xv.x = fmaxf(fmaf(xv.x, sc0, sh0), 0.f); xv.y = fmaxf(fmaf(xv.y, sc1, sh1), 0.f);
                xv.z = fmaxf(fmaf(xv.z, sc2, sh2), 0.f); xv.w = fmaxf(fmaf(xv.w, sc3, sh3), 0.f);
            }
            a0 += xv.x + tv.x; a1 += xv.y + tv.y; a2 += xv.z + tv.z; a3 += xv.w + tv.w;
        }
        *(float4*)(sA + (wv * 4 + q) * 68 + 4 * c15) = make_float4(a0, a1, a2, a3);
    }
    __syncthreads();

    // ---- A-frags to regs (sA dies after next sync; sH aliases) ----
    bf16x8 ah[2], al[2];
#pragma unroll
    for (int kt = 0; kt < 2; ++kt) {
        const float* p = sA + c15 * 68 + kt * 32 + q * 8;
        float4 x0 = *(const float4*)p;
        float4 x1 = *(const float4*)(p + 4);
        float xs[8] = {x0.x, x0.y, x0.z, x0.w, x1.x, x1.y, x1.z, x1.w};
#pragma unroll
        for (int j = 0; j < 8; ++j) {
            ushort_t hi, lo; bsplit(xs[j], hi, lo);
            ah[kt][j] = (short)hi; al[kt][j] = (short)lo;
        }
    }
    __syncthreads();

    // ---- GEMM1: nt = 2wv+j ----
    f32x4 acc1[2];
#pragma unroll
    for (int j = 0; j < 2; ++j) { f32x4 z = {0.f, 0.f, 0.f, 0.f}; acc1[j] = z; }
#pragma unroll
    for (int kt = 0; kt < 2; ++kt) {
#pragma unroll
        for (int j = 0; j < 2; ++j) {
            int nt = 2 * wv + j;
            size_t fo = ((size_t)((nt * 2 + kt) * 64 + lane)) * 8;
            bf16x8 bh = *(const bf16x8*)(w1h + fo);
            bf16x8 bl = *(const bf16x8*)(w1l + fo);
            acc1[j] = __builtin_amdgcn_mfma_f32_16x16x32_bf16(ah[kt], bh, acc1[j], 0, 0, 0);
            acc1[j] = __builtin_amdgcn_mfma_f32_16x16x32_bf16(al[kt], bh, acc1[j], 0, 0, 0);
            acc1[j] = __builtin_amdgcn_mfma_f32_16x16x32_bf16(ah[kt], bl, acc1[j], 0, 0, 0);
        }
    }
#pragma unroll
    for (int j = 0; j < 2; ++j) {
        int nt = 2 * wv + j;
        float bias = b1[nt * 16 + c15];
#pragma unroll
        for (int rg = 0; rg < 4; ++rg)
            sH[(4 * q + rg) * 132 + nt * 16 + c15] = fmaxf(acc1[j][rg] + bias, 0.f);
    }
    __syncthreads();

    // ---- GEMM2: nt = wv ----
    f32x4 acc2 = {0.f, 0.f, 0.f, 0.f};
#pragma unroll
    for (int kt = 0; kt < 4; ++kt) {
        const float* p = sH + c15 * 132 + kt * 32 + q * 8;
        float4 x0 = *(const float4*)p;
        float4 x1 = *(const float4*)(p + 4);
        float xs[8] = {x0.x, x0.y, x0.z, x0.w, x1.x, x1.y, x1.z, x1.w};
        bf16x8 a2h, a2l;
#pragma unroll
        for (int j = 0; j < 8; ++j) {
            ushort_t hi, lo; bsplit(xs[j], hi, lo);
            a2h[j] = (short)hi; a2l[j] = (short)lo;
        }
        size_t fo = ((size_t)((wv * 4 + kt) * 64 + lane)) * 8;
        bf16x8 bh = *(const bf16x8*)(w2h + fo);
        bf16x8 bl = *(const bf16x8*)(w2l + fo);
        acc2 = __builtin_amdgcn_mfma_f32_16x16x32_bf16(a2h, bh, acc2, 0, 0, 0);
        acc2 = __builtin_amdgcn_mfma_f32_16x16x32_bf16(a2l, bh, acc2, 0, 0, 0);
        acc2 = __builtin_amdgcn_mfma_f32_16x16x32_bf16(a2h, bl, acc2, 0, 0, 0);
    }
    {
        float bias = b2[wv * 16 + c15];
        float s = 0.f, s2 = 0.f;
#pragma unroll
        for (int rg = 0; rg < 4; ++rg) {
            float v = acc2[rg] + bias;
            hout[(size_t)(blockIdx.x * 16 + 4 * q + rg) * 64 + wv * 16 + c15] = v;
            s += v; s2 += v * v;
        }
        s += __shfl_xor(s, 16, 64);  s += __shfl_xor(s, 32, 64);
        s2 += __shfl_xor(s2, 16, 64); s2 += __shfl_xor(s2, 32, 64);
        if (q == 0) {
            float* ps = pstout + (size_t)(blockIdx.x & 31) * 128;
            atomicAdd(&ps[wv * 16 + c15], s);
            atomicAdd(&ps[64 + wv * 16 + c15], s2);
        }
    }
}

// ---------------- 2-set pooling (raw, no BN) ----------------
__global__ void kpool2(const float* __restrict__ h2, const int* __restrict__ a0,
                       float* __restrict__ xp) {
    int t = blockIdx.x * 256 + threadIdx.x;
    int j = t >> 4, c = t & 15;
    int na = a0[2 * j], nb = a0[2 * j + 1];
    float4 va = *(const float4*)(h2 + (size_t)na * 64 + 4 * c);
    float4 vb = *(const float4*)(h2 + (size_t)nb * 64 + 4 * c);
    float4 o = make_float4(0.5f * (va.x + vb.x), 0.5f * (va.y + vb.y),
                           0.5f * (va.z + vb.z), 0.5f * (va.w + vb.w));
    *(float4*)(xp + (size_t)j * 64 + 4 * c) = o;
}

// ---------------- GraphConv GEMMs; FIRST applies final-layer BN during staging + iso rows ----------------
template <int FIRST>
__global__ __launch_bounds__(256) void kgcmm(const float* __restrict__ X,
                                             const float* __restrict__ Wrel,
                                             const float* __restrict__ Wroot,
                                             const float* __restrict__ WrelIso,
                                             const float* __restrict__ WrootIso,
                                             const int* __restrict__ isoIdx,
                                             float* __restrict__ Yrel,
                                             float* __restrict__ Yroot,
                                             const float* __restrict__ pst,
                                             const float* __restrict__ g4,
                                             const float* __restrict__ b4) {
    __shared__ float sX[64 * 65];
    __shared__ float sR[64 * 64];
    __shared__ float sT[64 * 64];
    __shared__ float sstat[128];
    __shared__ float sSC[64], sSH[64];
    int tid = threadIdx.x, blk = blockIdx.x;
    if (FIRST && tid < 128) {
        float s = 0.f;
        const float* p = pst + tid;
#pragma unroll
        for (int i = 0; i < 32; ++i) s += p[i * 128];
        sstat[tid] = s;
    }
#pragma unroll
    for (int i = tid; i < 1024; i += 256) {
        ((float4*)sR)[i] = ((const float4*)Wrel)[i];
        ((float4*)sT)[i] = ((const float4*)Wroot)[i];
    }
    __syncthreads();
    if (FIRST && tid < 64) {
        float mu = sstat[tid] * (1.f / NN);
        float var = sstat[64 + tid] * (1.f / NN) - mu * mu;
        float sc = g4[tid] * rsqrtf(var + 1e-5f);
        sSC[tid] = sc;
        sSH[tid] = b4[tid] - mu * sc;
    }
    __syncthreads();
    const float4* x4 = (const float4*)(X + (size_t)blk * 4096);
#pragma unroll
    for (int i = tid; i < 1024; i += 256) {
        float4 v = x4[i];
        int row = i >> 4, c = (i & 15) << 2;
        if (FIRST) {
            v.x = fmaf(v.x, sSC[c], sSH[c]);
            v.y = fmaf(v.y, sSC[c + 1], sSH[c + 1]);
            v.z = fmaf(v.z, sSC[c + 2], sSH[c + 2]);
            v.w = fmaf(v.w, sSC[c + 3], sSH[c + 3]);
        }
        float* p = sX + row * 65 + c;
        p[0] = v.x; p[1] = v.y; p[2] = v.z; p[3] = v.w;
    }
    __syncthreads();
    int tm = tid >> 4, tn = tid & 15;
    float aR[4][4], aT[4][4];
#pragma unroll
    for (int r = 0; r < 4; ++r)
#pragma unroll
        for (int c = 0; c < 4; ++c) { aR[r][c] = 0.f; aT[r][c] = 0.f; }
    const float* xrow = sX + tm * 4 * 65;
#pragma unroll 4
    for (int k = 0; k < 64; ++k) {
        float a0 = xrow[k], a1 = xrow[65 + k], a2 = xrow[130 + k], a3 = xrow[195 + k];
        float4 br = *(const float4*)(sR + k * 64 + tn * 4);
        float4 bt = *(const float4*)(sT + k * 64 + tn * 4);
        float rb[4] = {br.x, br.y, br.z, br.w};
        float tb[4] = {bt.x, bt.y, bt.z, bt.w};
#pragma unroll
        for (int c = 0; c < 4; ++c) {
            aR[0][c] = fmaf(a0, rb[c], aR[0][c]); aR[1][c] = fmaf(a1, rb[c], aR[1][c]);
            aR[2][c] = fmaf(a2, rb[c], aR[2][c]); aR[3][c] = fmaf(a3, rb[c], aR[3][c]);
            aT[0][c] = fmaf(a0, tb[c], aT[0][c]); aT[1][c] = fmaf(a1, tb[c], aT[1][c]);
            aT[2][c] = fmaf(a2, tb[c], aT[2][c]); aT[3][c] = fmaf(a3, tb[c], aT[3][c]);
        }
    }
#pragma unroll
    for (int r = 0; r < 4; ++r) {
        int row = blk * 64 + tm * 4 + r;
        float4 vr = make_float4(aR[r][0], aR[r][1], aR[r][2], aR[r][3]);
        float4 vt = make_float4(aT[r][0], aT[r][1], aT[r][2], aT[r][3]);
        if (FIRST) {
            int ii = isoIdx[row];
            float4 er = *(const float4*)(WrelIso + (size_t)ii * 64 + tn * 4);
            float4 et = *(const float4*)(WrootIso + (size_t)ii * 64 + tn * 4);
            vr.x += er.x; vr.y += er.y; vr.z += er.z; vr.w += er.w;
            vt.x += et.x; vt.y += et.y; vt.z += et.z; vt.w += et.w;
        }
        *(float4*)(Yrel + (size_t)row * 64 + tn * 4) = vr;
        *(float4*)(Yroot + (size_t)row * 64 + tn * 4) = vt;
    }
}

// ---------------- GraphConv gather ----------------
__global__ void kgather2(const float* __restrict__ yrel, const float* __restrict__ yroot,
                         const float* __restrict__ brel, const int* __restrict__ offs,
                         const int* __restrict__ col, float* __restrict__ out) {
    int t = blockIdx.x * 256 + threadIdx.x;
    int j = t >> 4, c = t & 15;
    int s0 = offs[j], s1 = offs[j + 1];
    float4 rt = *(const float4*)(yroot + (size_t)j * 64 + 4 * c);
    float4 bb = *(const float4*)(brel + 4 * c);
    float a0 = rt.x + bb.x, a1 = rt.y + bb.y, a2 = rt.z + bb.z, a3 = rt.w + bb.w;
    int e = s0;
    for (; e + 4 <= s1; e += 4) {
        int v0 = col[e], v1 = col[e + 1], v2 = col[e + 2], v3 = col[e + 3];
        float4 x0 = *(const float4*)(yrel + (size_t)v0 * 64 + 4 * c);
        float4 x1 = *(const float4*)(yrel + (size_t)v1 * 64 + 4 * c);
        float4 x2 = *(const float4*)(yrel + (size_t)v2 * 64 + 4 * c);
        float4 x3 = *(const float4*)(yrel + (size_t)v3 * 64 + 4 * c);
        a0 += (x0.x + x1.x) + (x2.x + x3.x);
        a1 += (x0.y + x1.y) + (x2.y + x3.y);
        a2 += (x0.z + x1.z) + (x2.z + x3.z);
        a3 += (x0.w + x1.w) + (x2.w + x3.w);
    }
    for (; e < s1; ++e) {
        float4 x = *(const float4*)(yrel + (size_t)col[e] * 64 + 4 * c);
        a0 += x.x; a1 += x.y; a2 += x.z; a3 += x.w;
    }
    *(float4*)(out + (size_t)j * 64 + 4 * c) =
        make_float4(fmaxf(a0, 0.f), fmaxf(a1, 0.f), fmaxf(a2, 0.f), fmaxf(a3, 0.f));
}

// ---------------- per-graph mean pools (x1 gets final BN affine on the mean) ----------------
__global__ void kpoolg(const float* __restrict__ h2, const float* __restrict__ xp2,
                       const float* __restrict__ pst, const float* __restrict__ g4,
                       const float* __restrict__ b4, float* __restrict__ m) {
    __shared__ float sstat[128];
    __shared__ float red[4][64];
    int g = blockIdx.x, tid = threadIdx.x;
    if (tid < 128) {
        float s = 0.f;
        const float* p = pst + tid;
#pragma unroll
        for (int i = 0; i < 32; ++i) s += p[i * 128];
        sstat[tid] = s;
    }
    int wid = tid >> 6, d = tid & 63;
    float s1 = 0.f;
    for (int i = wid; i < 200; i += 4) s1 += h2[((size_t)g * 200 + i) * 64 + d];
    red[wid][d] = s1;
    __syncthreads();
    if (wid == 0) {
        float mean = (red[0][d] + red[1][d] + red[2][d] + red[3][d]) * (1.f / 200.f);
        float mu = sstat[d] * (1.f / NN);
        float var = sstat[64 + d] * (1.f / NN) - mu * mu;
        float sc = g4[d] * rsqrtf(var + 1e-5f);
        m[g * 128 + d] = fmaf(mean, sc, b4[d] - mu * sc);
    }
    __syncthreads();
    float s2 = 0.f;
    for (int i = wid; i < 400; i += 4) s2 += xp2[((size_t)g * 400 + i) * 64 + d];
    red[wid][d] = s2;
    __syncthreads();
    if (wid == 0) m[g * 128 + 64 + d] = (red[0][d] + red[1][d] + red[2][d] + red[3][d]) * (1.f / 400.f);
}

// ---------------- readout MLP ----------------
__global__ void kread(const float* __restrict__ m, const float* __restrict__ W0,
                      const float* __restrict__ b0, const float* __restrict__ W1,
                      const float* __restrict__ b1, const float* __restrict__ W2,
                      const float* __restrict__ b2, const float* __restrict__ lw,
                      const float* __restrict__ lb, float* __restrict__ out) {
    __shared__ float s0[64], s1[32], s2[16];
    int g = blockIdx.x, d = threadIdx.x;
    const float* mr = m + g * 128;
    float t = b0[d];
    for (int k = 0; k < 128; ++k) t = fmaf(mr[k], W0[k * 64 + d], t);
    s0[d] = fmaxf(t, 0.f);
    __syncthreads();
    if (d < 32) {
        float u = b1[d];
        for (int k = 0; k < 64; ++k) u = fmaf(s0[k], W1[k * 32 + d], u);
        s1[d] = fmaxf(u, 0.f);
    }
    __syncthreads();
    if (d < 16) {
        float u = b2[d];
        for (int k = 0; k < 32; ++k) u = fmaf(s1[k], W2[k * 16 + d], u);
        s2[d] = fmaxf(u, 0.f);
    }
    __syncthreads();
    if (d == 0) {
        float u = lb[0];
        for (int k = 0; k < 16; ++k) u = fmaf(s2[k], lw[k], u);
        out[g] = u;
    }
}

// ---------------- host ----------------
extern "C" void kernel_launch(void* const* d_in, const int* in_sizes, int n_in,
                              void* d_out, int out_size, void* d_ws, size_t ws_size,
                              hipStream_t stream) {
    if (ws_size < WS_NEEDED) return;

    const float* x    = (const float*)d_in[0];
    const int*   ei   = (const int*)d_in[1];
    const int*   ea   = (const int*)d_in[2];
    const float* iso  = (const float*)d_in[4];
    const int*   ei2  = (const int*)d_in[5];
    const int*   ai2  = (const int*)d_in[6];
    const float* embW = (const float*)d_in[8];
    const float* embB = (const float*)d_in[9];
    const float* gW1  = (const float*)d_in[10];
    const float* gB1  = (const float*)d_in[11];
    const float* gW2  = (const float*)d_in[12];
    const float* gB2  = (const float*)d_in[13];
    const float* ee1  = (const float*)d_in[14];
    const float* ee2  = (const float*)d_in[15];
    const float* bng  = (const float*)d_in[16];
    const float* bnb  = (const float*)d_in[17];
    const float* i1rW = (const float*)d_in[18];
    const float* i1rB = (const float*)d_in[19];
    const float* i1tW = (const float*)d_in[20];
    const float* i2rW = (const float*)d_in[21];
    const float* i2rB = (const float*)d_in[22];
    const float* i2tW = (const float*)d_in[23];
    const float* roW0 = (const float*)d_in[24];
    const float* roB0 = (const float*)d_in[25];
    const float* roW1 = (const float*)d_in[26];
    const float* roB1 = (const float*)d_in[27];
    const float* roW2 = (const float*)d_in[28];
    const float* roB2 = (const float*)d_in[29];
    const float* lW   = (const float*)d_in[30];
    const float* lB   = (const float*)d_in[31];
    float* out = (float*)d_out;

    char* ws = (char*)d_ws;
    float* h      = (float*)(ws + OFF_H);
    float* hB     = (float*)(ws + OFF_AGG);    // ping-pong buffer B
    float* hA     = (float*)(ws + OFF_H2);     // ping-pong buffer A; final h2
    float* h2     = hA;
    float* xp     = (float*)(ws + OFF_XP);
    float* yrel   = (float*)(ws + OFF_H);      // spans h+hB (both dead post-GIN)
    float* yroot  = (float*)(ws + OFF_YROOT);
    int* offs1    = (int*)(ws + OFF_OFFS1);
    int* col1     = (int*)(ws + OFF_COL1);
    int* offs2    = (int*)(ws + OFF_OFFS2);
    int* col2     = (int*)(ws + OFF_COL2);
    int* cnt1     = (int*)(ws + OFF_CNT1);
    int* cnt2     = (int*)(ws + OFF_CNT2);
    int* isoIdx   = (int*)(ws + OFF_ISO);
    float* mbuf   = (float*)(ws + OFF_M);
    int* bsum1    = (int*)(ws + OFF_M);
    int* boffs1   = (int*)(ws + OFF_M + 256);
    int* bsum2    = (int*)(ws + OFF_M + 512);
    int* boffs2   = (int*)(ws + OFF_M + 1024);
    ushort_t* w1h = (ushort_t*)(ws + OFF_YROOT);
    ushort_t* w1l = (ushort_t*)(ws + OFF_YROOT + 81920);
    ushort_t* w2h = (ushort_t*)(ws + OFF_YROOT + 163840);
    ushort_t* w2l = (ushort_t*)(ws + OFF_YROOT + 245760);
    float* pstat2 = (float*)(ws + OFF_CUR1);   // zeroed by memset each launch
    int* rank1    = (int*)(ws + OFF_XP);       // xp dead until kpool2
    int* rank2    = (int*)(ws + OFF_XP + (size_t)EE * 4);

    const int* src1 = ei;
    const int* dst1 = ei + EE;
    const int* src2 = ei2;
    const int* dst2 = ei2 + EE2;
    const int* a0   = ai2;

    hipMemsetAsync(ws + OFF_CNT1, 0, ZERO_BYTES, stream);

    // CSR build (R11 structure: rank capture + atomic-free fill)
    khist_m<<<1200, 256, 0, stream>>>(dst1, dst2, cnt1, cnt2, rank1, rank2);
    kprepx<<<13240, 256, 0, stream>>>(x, embW, embB, h, gW1, gW2,
                                      w1h, w1l, w2h, w2l, iso, isoIdx);
    kreduce_m<<<150, 256, 0, stream>>>(cnt1, cnt2, bsum1, bsum2);
    kscan_small_m<<<2, 128, 0, stream>>>(bsum1, bsum2, boffs1, boffs2);
    kscan_apply_m<<<150, 256, 0, stream>>>(cnt1, cnt2, boffs1, boffs2, offs1, offs2);
    kfill_m<<<1200, 256, 0, stream>>>(src1, dst1, ea, rank1, offs1, col1,
                                      src2, dst2, rank2, offs2, col2);

    // GIN layers: fused gather+MLP, h ping-pong (layer 4 lands in hA = h2)
    for (int l = 0; l < LL; ++l) {
        const float* hin = (l == 0) ? h : ((l & 1) ? hA : hB);
        float* hout = (l & 1) ? hB : hA;
        if (l == 0) {
            kglayer<0><<<NN / 16, 256, 0, stream>>>(
                hin, hout, offs1, col1, ee1, ee2,
                w1h, w1l, w2h, w2l, gB1, gB2,
                nullptr, nullptr, nullptr, pstat2);
        } else {
            kglayer<1><<<NN / 16, 256, 0, stream>>>(
                hin, hout, offs1, col1, ee1 + l * 384, ee2 + l * 192,
                w1h + (size_t)l * 8192, w1l + (size_t)l * 8192,
                w2h + (size_t)l * 8192, w2l + (size_t)l * 8192,
                gB1 + l * 128, gB2 + l * 64,
                pstat2 + (size_t)(l - 1) * 4096,
                bng + (l - 1) * 64, bnb + (l - 1) * 64,
                pstat2 + (size_t)l * 4096);
        }
    }

    // 2-set branch (final-layer BN folded into kgcmm<1> staging and kpoolg mean)
    kpool2<<<NN2 * 16 / 256, 256, 0, stream>>>(h2, a0, xp);
    kgcmm<1><<<NN2 / 64, 256, 0, stream>>>(xp, i1rW, i1tW, i1rW + 64 * 64,
                                           i1tW + 64 * 64, isoIdx, yrel, yroot,
                                           pstat2 + (size_t)4 * 4096,
                                           bng + 4 * 64, bnb + 4 * 64);
    kgather2<<<NN2 * 16 / 256, 256, 0, stream>>>(yrel, yroot, i1rB, offs2, col2, xp);
    kgcmm<0><<<NN2 / 64, 256, 0, stream>>>(xp, i2rW, i2tW, nullptr, nullptr,
                                           nullptr, yrel, yroot,
                                           nullptr, nullptr, nullptr);
    kgather2<<<NN2 * 16 / 256, 256, 0, stream>>>(yrel, yroot, i2rB, offs2, col2, xp);

    // pools + readout
    kpoolg<<<GG, 256, 0, stream>>>(h2, xp, pstat2 + (size_t)4 * 4096,
                                   bng + 4 * 64, bnb + 4 * 64, mbuf);
    kread<<<GG, 64, 0, stream>>>(mbuf, roW0, roB0, roW1, roB1, roW2, roB2, lW, lB, out);
}